// Round 2
// baseline (112.351 us; speedup 1.0000x reference)
//
#include <hip/hip_runtime.h>

// TensorRelaxationPooling: B=8, T=4096, D=128, NB=32, STRIDE=2
//   z1 = 0.5*G*(X@E + bx), z2 = X@F + by    (g folded into z1)
//   out[p] = z1[2p] (x) z2[2p] + z1[2p+1] (x) z2[2p+1]   -> [16384, 1024] fp32
//
// Structure: 512 blocks x 128 threads (2 waves). Block owns 64 raw frames.
// Thread tile: 8 frames (two 4-frame clusters at +32) x 4 basis cols ->
// 12 ds_read_b128 per 128 FMA (LDS-pipe is the bottleneck; minimize its instrs).
// Wave-private pooling: wave w pools only its own 32 frames; z overlays the
// wave's OWN X rows in LDS, so no cross-wave hazard and stores drain while
// other waves/blocks still compute.

#define DIN 128
#define NB_ 32

constexpr int FR   = 64;    // raw frames per block
constexpr int SXS  = 132;   // X-tile row stride (floats): 16B-aligned, 2-way-free for 4-frame strides
constexpr int SWS  = 68;    // W row stride (floats): breaks 8-way conflict on staging writes
constexpr int SZS  = 68;    // z row stride (floats)
constexpr int NBLK = (8 * 4096) / FR;  // 512

__global__ __launch_bounds__(128) void trp_fused(
    const float* __restrict__ X, const float* __restrict__ E,
    const float* __restrict__ F, const float* __restrict__ G,
    const float* __restrict__ bx, const float* __restrict__ by,
    float* __restrict__ out)
{
    __shared__ __align__(16) float sw[DIN * SWS];  // W = [E|F], padded. 34.8 KB
    __shared__ __align__(16) float sxz[FR * SXS];  // X tile; z overlays per-wave. 33.8 KB

    const int tid = threadIdx.x;
    const int blk = blockIdx.x;

    // ---- stage W = [E|F] (row d: 16 float4 = E row | F row) ----
    #pragma unroll
    for (int it = 0; it < 16; ++it) {
        int v = tid + 128 * it;       // float4 index, 2048 total
        int d = v >> 4, c = v & 15;
        const float* src = (c < 8) ? (E + d * NB_ + c * 4)
                                   : (F + d * NB_ + (c - 8) * 4);
        *(float4*)&sw[d * SWS + c * 4] = *(const float4*)src;
    }
    // ---- stage X tile (64 frames, contiguous in global) ----
    const float* xb = X + (size_t)blk * FR * DIN;
    #pragma unroll
    for (int it = 0; it < 16; ++it) {
        int v = tid + 128 * it;       // float4 index, 2048 total
        int f = v >> 5, dc = v & 31;
        *(float4*)&sxz[f * SXS + dc * 4] = *(const float4*)(xb + f * DIN + dc * 4);
    }
    __syncthreads();

    const int wave = tid >> 6;            // 0..1
    const int n0   = (tid & 15) * 4;      // basis col base 0..60 (z1|z2)
    const int fg   = (tid >> 4) & 3;      // frame group in wave
    const int fA   = wave * 16 + fg * 4;  // cluster A first frame; cluster B = fA+32

    float acc[2][4][4];
    #pragma unroll
    for (int cl = 0; cl < 2; ++cl)
        #pragma unroll
        for (int q = 0; q < 4; ++q)
            #pragma unroll
            for (int c = 0; c < 4; ++c) acc[cl][q][c] = 0.f;

    #pragma unroll 2
    for (int dc = 0; dc < DIN / 4; ++dc) {
        const int d4 = dc * 4;
        float w[4][4];
        #pragma unroll
        for (int r = 0; r < 4; ++r)
            *(float4*)&w[r][0] = *(const float4*)&sw[(d4 + r) * SWS + n0];
        #pragma unroll
        for (int cl = 0; cl < 2; ++cl) {
            #pragma unroll
            for (int q = 0; q < 4; ++q) {
                float x[4];
                *(float4*)&x[0] = *(const float4*)&sxz[(fA + cl * 32 + q) * SXS + d4];
                #pragma unroll
                for (int r = 0; r < 4; ++r)
                    #pragma unroll
                    for (int c = 0; c < 4; ++c)
                        acc[cl][q][c] = fmaf(x[r], w[r][c], acc[cl][q][c]);
            }
        }
    }

    // ---- bias (+ fold 0.5*G into the z1 half) ----
    float bias[4], scale;
    if (n0 < NB_) { *(float4*)bias = *(const float4*)(bx + n0);       scale = 0.5f * G[0]; }
    else          { *(float4*)bias = *(const float4*)(by + n0 - NB_); scale = 1.0f; }

    // ---- write z into this wave's own X-row regions (no cross-wave hazard) ----
    #pragma unroll
    for (int cl = 0; cl < 2; ++cl) {
        const int zb = (cl * 32 + wave * 16) * SXS;  // region start (float offset)
        #pragma unroll
        for (int q = 0; q < 4; ++q) {
            float4 z;
            z.x = (acc[cl][q][0] + bias[0]) * scale;
            z.y = (acc[cl][q][1] + bias[1]) * scale;
            z.z = (acc[cl][q][2] + bias[2]) * scale;
            z.w = (acc[cl][q][3] + bias[3]) * scale;
            *(float4*)&sxz[zb + (fg * 4 + q) * SZS + n0] = z;
        }
    }
    __syncthreads();  // cheap: only 2 waves in block; guards LDS write->cross-lane read

    // ---- epilogue: outer products + pair pooling, wave-private ----
    const int lane = tid & 63;
    const int j4 = lane & 7;     // z2 float4-column
    const int i0 = lane >> 3;    // z1 row base (i = i0 + 8t)
    float4* out4 = (float4*)out;
    const int pooledBase = blk * 32;

    #pragma unroll
    for (int cl = 0; cl < 2; ++cl) {
        const int zb = (cl * 32 + wave * 16) * SXS;
        const int pfBase = pooledBase + cl * 16 + wave * 8;
        #pragma unroll 2
        for (int pp = 0; pp < 8; ++pp) {
            const float* zr0 = &sxz[zb + (2 * pp) * SZS];
            const float* zr1 = zr0 + SZS;
            float4 v0 = *(const float4*)&zr0[NB_ + 4 * j4];
            float4 v1 = *(const float4*)&zr1[NB_ + 4 * j4];
            float4* ob = out4 + (size_t)(pfBase + pp) * 256 + lane;
            #pragma unroll
            for (int t = 0; t < 4; ++t) {
                const int i = i0 + 8 * t;
                float a0 = zr0[i];   // z1 (pre-scaled by 0.5*G)
                float a1 = zr1[i];
                float4 r;
                r.x = fmaf(a0, v0.x, a1 * v1.x);
                r.y = fmaf(a0, v0.y, a1 * v1.y);
                r.z = fmaf(a0, v0.z, a1 * v1.z);
                r.w = fmaf(a0, v0.w, a1 * v1.w);
                ob[64 * t] = r;
            }
        }
    }
}

extern "C" void kernel_launch(void* const* d_in, const int* in_sizes, int n_in,
                              void* d_out, int out_size, void* d_ws, size_t ws_size,
                              hipStream_t stream) {
    const float* X  = (const float*)d_in[0];
    const float* E  = (const float*)d_in[1];
    const float* F  = (const float*)d_in[2];
    const float* G  = (const float*)d_in[3];
    const float* bx = (const float*)d_in[4];
    const float* by = (const float*)d_in[5];
    float* outp = (float*)d_out;
    trp_fused<<<dim3(NBLK), dim3(128), 0, stream>>>(X, E, F, G, bx, by, outp);
}

// Round 3
// 109.795 us; speedup vs baseline: 1.0233x; 1.0233x over previous
//
#include <hip/hip_runtime.h>

// TensorRelaxationPooling: B=8, T=4096, D=128, NB=32, STRIDE=2
//   z1 = 0.5*G*(X@E + bx), z2 = X@F + by    (scale folded into z1)
//   out[p] = z1[2p] (x) z2[2p] + z1[2p+1] (x) z2[2p+1]   -> [16384, 1024] fp32
//
// R3 structure: 512 blocks x 256 threads (4 waves), block owns 64 raw frames.
// Wave w privately owns frames [16w, 16w+16): it computes their z rows,
// overlays them IN PLACE over its own X rows (stride SXS), and pools/stores
// them -- zero barriers after the staging barrier. 8 waves/CU (2 blocks/CU,
// 65.8 KB LDS) for latency hiding; barrier-free tail lets each wave's stores
// drain under other waves' GEMM.

#define DIN 128
#define NB_ 32

constexpr int FR   = 64;    // raw frames per block
constexpr int SXS  = 132;   // X/z row stride (floats): 16B-aligned, breaks pow2 bank stride
constexpr int NBLK = (8 * 4096) / FR;  // 512

__global__ __launch_bounds__(256) void trp_fused(
    const float* __restrict__ X, const float* __restrict__ E,
    const float* __restrict__ F, const float* __restrict__ G,
    const float* __restrict__ bx, const float* __restrict__ by,
    float* __restrict__ out)
{
    __shared__ __align__(16) float sw[DIN * 64];   // W = [E|F], 32 KB
    __shared__ __align__(16) float sxz[FR * SXS];  // X tile; z overlays per-wave. 33.8 KB

    const int tid = threadIdx.x;
    const int blk = blockIdx.x;

    // ---- hoist tiny global loads: latency hides under staging + GEMM ----
    const int n0 = (tid & 15) * 4;   // basis col base 0..60 (z1|z2 concat)
    float bias[4], scale;
    if (n0 < NB_) { *(float4*)bias = *(const float4*)(bx + n0);       scale = 0.5f * G[0]; }
    else          { *(float4*)bias = *(const float4*)(by + n0 - NB_); scale = 1.0f; }
    float bs[4];
    #pragma unroll
    for (int c = 0; c < 4; ++c) bs[c] = bias[c] * scale;

    // ---- stage W = [E|F]: row d = 16 float4 (E row | F row) ----
    #pragma unroll
    for (int it = 0; it < 8; ++it) {
        int v = tid + 256 * it;       // float4 index, 2048 total
        int d = v >> 4, c = v & 15;
        const float* src = (c < 8) ? (E + d * NB_ + c * 4)
                                   : (F + d * NB_ + (c - 8) * 4);
        *(float4*)&sw[d * 64 + c * 4] = *(const float4*)src;
    }
    // ---- stage X tile (64 frames contiguous in global) ----
    const float* xb = X + (size_t)blk * FR * DIN;
    #pragma unroll
    for (int it = 0; it < 8; ++it) {
        int v = tid + 256 * it;
        int f = v >> 5, dc = v & 31;
        *(float4*)&sxz[f * SXS + dc * 4] = *(const float4*)(xb + f * DIN + dc * 4);
    }
    __syncthreads();   // the ONLY barrier

    // ---- register-tiled GEMM: thread = 4 frames x 4 basis cols ----
    const int f0 = (tid >> 4) * 4;   // wave w owns f0 in [16w, 16w+12]

    float acc[4][4];
    #pragma unroll
    for (int q = 0; q < 4; ++q)
        #pragma unroll
        for (int c = 0; c < 4; ++c) acc[q][c] = 0.f;

    #pragma unroll 2
    for (int dc = 0; dc < DIN / 4; ++dc) {
        const int d4 = dc * 4;
        float w[4][4];
        #pragma unroll
        for (int r = 0; r < 4; ++r)
            *(float4*)&w[r][0] = *(const float4*)&sw[(d4 + r) * 64 + n0];
        #pragma unroll
        for (int q = 0; q < 4; ++q) {
            float x[4];
            *(float4*)&x[0] = *(const float4*)&sxz[(f0 + q) * SXS + d4];
            #pragma unroll
            for (int r = 0; r < 4; ++r)
                #pragma unroll
                for (int c = 0; c < 4; ++c)
                    acc[q][c] = fmaf(x[r], w[r][c], acc[q][c]);
        }
    }

    // ---- overlay z in place over this wave's OWN X rows: no barrier ----
    // z row f lives at &sxz[f*SXS], cols 0..63 (z1 pre-scaled by 0.5*G).
    // Wave-lockstep + in-order per-wave LDS ordering make this safe.
    #pragma unroll
    for (int q = 0; q < 4; ++q) {
        float4 z;
        z.x = fmaf(acc[q][0], scale, bs[0]);
        z.y = fmaf(acc[q][1], scale, bs[1]);
        z.z = fmaf(acc[q][2], scale, bs[2]);
        z.w = fmaf(acc[q][3], scale, bs[3]);
        *(float4*)&sxz[(f0 + q) * SXS + n0] = z;
    }

    // ---- wave-private epilogue: outer products + pair pooling ----
    const int wave = tid >> 6;
    const int lane = tid & 63;
    const int j4 = lane & 7;     // z2 float4-column
    const int i0 = lane >> 3;    // z1 row base (i = i0 + 8t)
    float4* out4 = (float4*)out;
    const int pfBase = blk * 32 + wave * 8;   // this wave's pooled frames

    #pragma unroll 2
    for (int pp = 0; pp < 8; ++pp) {
        const float* zr0 = &sxz[(wave * 16 + 2 * pp) * SXS];
        const float* zr1 = zr0 + SXS;
        float4 v0 = *(const float4*)&zr0[NB_ + 4 * j4];   // z2, frame 2p
        float4 v1 = *(const float4*)&zr1[NB_ + 4 * j4];   // z2, frame 2p+1
        float4* ob = out4 + (size_t)(pfBase + pp) * 256 + lane;
        #pragma unroll
        for (int t = 0; t < 4; ++t) {
            const int i = i0 + 8 * t;
            float a0 = zr0[i];   // z1 (pre-scaled)
            float a1 = zr1[i];
            float4 r;
            r.x = fmaf(a0, v0.x, a1 * v1.x);
            r.y = fmaf(a0, v0.y, a1 * v1.y);
            r.z = fmaf(a0, v0.z, a1 * v1.z);
            r.w = fmaf(a0, v0.w, a1 * v1.w);
            ob[64 * t] = r;
        }
    }
}

extern "C" void kernel_launch(void* const* d_in, const int* in_sizes, int n_in,
                              void* d_out, int out_size, void* d_ws, size_t ws_size,
                              hipStream_t stream) {
    const float* X  = (const float*)d_in[0];
    const float* E  = (const float*)d_in[1];
    const float* F  = (const float*)d_in[2];
    const float* G  = (const float*)d_in[3];
    const float* bx = (const float*)d_in[4];
    const float* by = (const float*)d_in[5];
    float* outp = (float*)d_out;
    trp_fused<<<dim3(NBLK), dim3(256), 0, stream>>>(X, E, F, G, bx, by, outp);
}

// Round 4
// 95.011 us; speedup vs baseline: 1.1825x; 1.1556x over previous
//
#include <hip/hip_runtime.h>

// TensorRelaxationPooling: B=8, T=4096, D=128, NB=32, STRIDE=2
//   z1 = X@E + bx, z2 = X@F + by   [32768, 32] each
//   out[p, i*32+j] = 0.5*G*(z1[2p,i]*z2[2p,j] + z1[2p+1,i]*z2[2p+1,j])
//
// R4 = R1 structure restored (measured best: 96.6 us total).
// Regression evidence (R2/R3): wave-private pooling epilogues cost ~13 us;
// the block-interleaved epilogue below (all 4 waves sweep one pooled frame
// per step, strictly sequential output) is the fast variant. Changes vs R1:
//   - sw row stride 64 -> 68: breaks 4-way bank conflict on W staging writes
//   - bias/G loads hoisted above staging (latency hides under GEMM)

#define DIN 128
#define NB_ 32

constexpr int N2   = 64;   // z1|z2 concatenated basis dim
constexpr int FR   = 64;   // raw frames per block
constexpr int POOL = 32;   // pooled frames per block
constexpr int SWS  = 68;   // W row stride (floats): 16B-aligned, breaks 4-way staging conflict
constexpr int SXS  = 132;  // LDS X-tile row stride (floats)
constexpr int SZS  = 68;   // LDS Z row stride (floats)
constexpr int NBLK = (8 * 4096) / FR;  // 512

__global__ __launch_bounds__(256) void trp_fused(
    const float* __restrict__ X, const float* __restrict__ E,
    const float* __restrict__ F, const float* __restrict__ G,
    const float* __restrict__ bx, const float* __restrict__ by,
    float* __restrict__ out)
{
    __shared__ __align__(16) float sw[DIN * SWS];  // W[d][n] = [E | F], 34.8 KB
    __shared__ __align__(16) float sxz[FR * SXS];  // X tile; Z overlays after K-loop. 33.8 KB

    const int tid = threadIdx.x;
    const int blk = blockIdx.x;

    // --- hoist tiny global loads; latency hides under staging + GEMM ---
    const int n0 = (tid & 15) * 4;   // basis col base (0..60)
    float bias[4];
    float g2 = 0.5f * G[0];
    if (n0 < NB_) *(float4*)bias = *(const float4*)(bx + n0);
    else          *(float4*)bias = *(const float4*)(by + (n0 - NB_));

    // --- stage W = [E | F] into LDS: 2048 float4, 8 per thread, coalesced ---
    #pragma unroll
    for (int it = 0; it < 8; ++it) {
        int v = tid + 256 * it;        // float4 index
        int d = v >> 4, c = v & 15;    // row, float4-column of sw
        const float* src = (c < 8) ? (E + d * NB_ + c * 4)
                                   : (F + d * NB_ + (c - 8) * 4);
        float4 val = *(const float4*)src;
        *(float4*)&sw[d * SWS + c * 4] = val;
    }
    // --- stage X tile (64 frames contiguous in global) ---
    const float* xb = X + (size_t)blk * FR * DIN;
    #pragma unroll
    for (int it = 0; it < 8; ++it) {
        int v = tid + 256 * it;
        int f = v >> 5, dc = v & 31;
        float4 val = *(const float4*)(xb + f * DIN + dc * 4);
        *(float4*)&sxz[f * SXS + dc * 4] = val;
    }
    __syncthreads();

    // --- register-tiled GEMM: thread owns 4 frames x 4 basis cols ---
    const int f0 = (tid >> 4) * 4;   // frame base (0..60)

    float acc[4][4];
    #pragma unroll
    for (int q = 0; q < 4; ++q)
        #pragma unroll
        for (int c = 0; c < 4; ++c) acc[q][c] = 0.f;

    #pragma unroll 2
    for (int dc = 0; dc < DIN / 4; ++dc) {
        const int d4 = dc * 4;
        float w[4][4];
        #pragma unroll
        for (int r = 0; r < 4; ++r)
            *(float4*)&w[r][0] = *(const float4*)&sw[(d4 + r) * SWS + n0];
        #pragma unroll
        for (int q = 0; q < 4; ++q) {
            float x[4];
            *(float4*)&x[0] = *(const float4*)&sxz[(f0 + q) * SXS + d4];
            #pragma unroll
            for (int r = 0; r < 4; ++r)
                #pragma unroll
                for (int c = 0; c < 4; ++c)
                    acc[q][c] = fmaf(x[r], w[r][c], acc[q][c]);
        }
    }

    // --- add bias, overlay Z into the X-tile LDS region (compact, stride 68) ---
    __syncthreads();  // everyone done reading sxz as X before we overwrite as Z
    #pragma unroll
    for (int q = 0; q < 4; ++q) {
        float4 z;
        z.x = acc[q][0] + bias[0];
        z.y = acc[q][1] + bias[1];
        z.z = acc[q][2] + bias[2];
        z.w = acc[q][3] + bias[3];
        *(float4*)&sxz[(f0 + q) * SZS + n0] = z;
    }
    __syncthreads();

    // --- epilogue: outer products + pair-pooling, block-interleaved stores ---
    // Thread writes output float4 index `tid` of each pooled frame: the block
    // sweeps 32 sequential 4KB frames -- the store pattern that measured best.
    const int i = tid >> 3;
    const int j = (tid & 7) * 4;
    float4* outv = (float4*)out + (size_t)blk * (POOL * 256) + tid;
    #pragma unroll 4
    for (int p = 0; p < POOL; ++p) {
        const float* zr0 = &sxz[(2 * p) * SZS];
        const float* zr1 = zr0 + SZS;
        float a0 = zr0[i];                                  // z1 frame 2p,   basis i
        float a1 = zr1[i];                                  // z1 frame 2p+1, basis i
        float4 v0 = *(const float4*)&zr0[NB_ + j];          // z2 frame 2p,   basis j..j+3
        float4 v1 = *(const float4*)&zr1[NB_ + j];          // z2 frame 2p+1
        float4 r;
        r.x = g2 * fmaf(a0, v0.x, a1 * v1.x);
        r.y = g2 * fmaf(a0, v0.y, a1 * v1.y);
        r.z = g2 * fmaf(a0, v0.z, a1 * v1.z);
        r.w = g2 * fmaf(a0, v0.w, a1 * v1.w);
        outv[p * 256] = r;
    }
}

extern "C" void kernel_launch(void* const* d_in, const int* in_sizes, int n_in,
                              void* d_out, int out_size, void* d_ws, size_t ws_size,
                              hipStream_t stream) {
    const float* X  = (const float*)d_in[0];
    const float* E  = (const float*)d_in[1];
    const float* F  = (const float*)d_in[2];
    const float* G  = (const float*)d_in[3];
    const float* bx = (const float*)d_in[4];
    const float* by = (const float*)d_in[5];
    float* outp = (float*)d_out;
    trp_fused<<<dim3(NBLK), dim3(256), 0, stream>>>(X, E, F, G, bx, by, outp);
}